// Round 3
// baseline (5055.801 us; speedup 1.0000x reference)
//
#include <hip/hip_runtime.h>
#include <cstddef>
#include <cstdint>

// ---------------- problem dims ----------------
#define T_ 32
#define A_ 32
#define F_ 4
#define E_ 256
#define FE_ 1024
#define H_ 768
#define H2_ 1536
#define G4_ 3072     // 4*H
#define G8_ 6144     // 4*H2
#define DTOK_ 256
#define DDEC_ 1280
#define SEQ_ 1024    // T*A

// ---------------- ws layout (float offsets) ----------------
constexpr size_t OFF_PACKED  = 0;                          // 1024*1024
constexpr size_t OFF_XF      = OFF_PACKED + 1024ull*1024;  // 1024*3072 (swizzled)
constexpr size_t OFF_XB      = OFF_XF + 1024ull*3072;
constexpr size_t OFF_XD      = OFF_XB + 1024ull*3072;      // 32*6144 (swizzled)
constexpr size_t OFF_XDIN    = OFF_XD + 32*6144;           // 32*1280
constexpr size_t OFF_ENC     = OFF_XDIN + 32*1280;         // 1024*1536
constexpr size_t OFF_HN      = OFF_ENC + 1024ull*1536;     // 32*1536
constexpr size_t OFF_AMAT    = OFF_HN + 32*1536;           // 32*1536
constexpr size_t OFF_C0      = OFF_AMAT + 32*1536;         // 1536
constexpr size_t OFF_PAIRS_E = OFF_C0 + 1536;              // 2dir x 2par x 768 u64 = 6144 floats
constexpr size_t OFF_PAIRS_D = OFF_PAIRS_E + 6144;         // 2par x 1536 u64 = 6144 floats
constexpr size_t MEMSET_BYTES = (6144 + 6144) * 4;         // 49152

__device__ __forceinline__ float sigf(float x) { return 1.f / (1.f + __expf(-x)); }

// ---------------- embed + decoder-input gather ----------------
__global__ void embed_k(const int* __restrict__ lattice, const int* __restrict__ inputs,
                        const int* __restrict__ gold, const int* __restrict__ sos,
                        const float* __restrict__ emb, const float* __restrict__ tok_emb,
                        float* __restrict__ packed, float* __restrict__ xdec_in) {
    int b = blockIdx.x, tid = threadIdx.x;
    if (b < SEQ_) {
        #pragma unroll
        for (int f = 0; f < F_; ++f) {
            int vid = lattice[b * F_ + f];
            packed[(size_t)b * FE_ + f * E_ + tid] = emb[(size_t)vid * E_ + tid];
        }
    } else {
        int t = b - SEQ_;  // 0..31
        for (int j = tid; j < DDEC_; j += 256) {
            float v;
            if (j < FE_) {
                int f = j >> 8, e2 = j & 255;
                int vid = (t == 0) ? sos[f]
                                   : lattice[(((t - 1) * A_) + gold[t - 1]) * F_ + f];
                v = emb[(size_t)vid * E_ + e2];
            } else {
                v = tok_emb[(size_t)inputs[t] * DTOK_ + (j - FE_)];
            }
            xdec_in[(size_t)t * DDEC_ + j] = v;
        }
    }
}

// ---------------- fp32 tiled GEMM: C[M,N] = A[M,K] @ B[K,N] + bias ----------------
// swh != 0: gate-interleaved output swizzle for the LSTM consumers:
//   n = q*swh + j  (q = gate, j = hidden col) -> n' = (j/12)*48 + (j%12)*4 + q.
// BN=128 never crosses a gate boundary (swh % 128 == 0), so q is tile-uniform.
#define BM 128
#define BN 128
#define BK 8
__device__ __forceinline__ void gemm_body(
    const float* __restrict__ A, const float* __restrict__ B,
    const float* __restrict__ bias, float* __restrict__ C,
    int M, int N, int K, int n0, int m0, int swh) {
    __shared__ float As[BK][BM + 4];
    __shared__ float Bs[BK][BN + 4];
    int tid = threadIdx.x;
    int tx = tid & 15, ty = tid >> 4;
    int lam = tid >> 1, lak = (tid & 1) * 4;
    int lbk = tid >> 5, lbn = (tid & 31) * 4;
    float acc[8][8] = {};
    for (int k0 = 0; k0 < K; k0 += BK) {
        float4 av = make_float4(0.f, 0.f, 0.f, 0.f);
        if (m0 + lam < M)
            av = *(const float4*)(A + (size_t)(m0 + lam) * K + k0 + lak);
        float4 bv = *(const float4*)(B + (size_t)(k0 + lbk) * N + n0 + lbn);
        __syncthreads();
        As[lak + 0][lam] = av.x; As[lak + 1][lam] = av.y;
        As[lak + 2][lam] = av.z; As[lak + 3][lam] = av.w;
        *(float4*)&Bs[lbk][lbn] = bv;
        __syncthreads();
        #pragma unroll
        for (int kk = 0; kk < BK; ++kk) {
            float a[8], b[8];
            *(float4*)&a[0] = *(const float4*)&As[kk][ty * 8];
            *(float4*)&a[4] = *(const float4*)&As[kk][ty * 8 + 4];
            *(float4*)&b[0] = *(const float4*)&Bs[kk][tx * 8];
            *(float4*)&b[4] = *(const float4*)&Bs[kk][tx * 8 + 4];
            #pragma unroll
            for (int i = 0; i < 8; ++i)
                #pragma unroll
                for (int j = 0; j < 8; ++j)
                    acc[i][j] += a[i] * b[j];
        }
    }
    int qg = 0, jb = 0;
    if (swh) { qg = n0 / swh; jb = n0 - qg * swh; }
    #pragma unroll
    for (int i = 0; i < 8; ++i) {
        int m = m0 + ty * 8 + i;
        if (m >= M) break;
        #pragma unroll
        for (int j = 0; j < 8; ++j) {
            int n = n0 + tx * 8 + j;
            float bb = bias ? bias[n] : 0.f;
            float v = acc[i][j] + bb;
            if (swh) {
                int jc = jb + tx * 8 + j;
                n = (jc / 12) * 48 + (jc % 12) * 4 + qg;
            }
            C[(size_t)m * N + n] = v;
        }
    }
}

__global__ __launch_bounds__(256) void gemm_bias_k(
    const float* __restrict__ A, const float* __restrict__ B,
    const float* __restrict__ bias, float* __restrict__ C,
    int M, int N, int K, int swh) {
    gemm_body(A, B, bias, C, M, N, K, blockIdx.x * BN, blockIdx.y * BM, swh);
}

__global__ __launch_bounds__(256) void gemm_bias2_k(
    const float* __restrict__ A,
    const float* __restrict__ B0, const float* __restrict__ bias0, float* __restrict__ C0,
    const float* __restrict__ B1, const float* __restrict__ bias1, float* __restrict__ C1,
    int M, int N, int K, int swh) {
    const float* B = blockIdx.z ? B1 : B0;
    const float* bias = blockIdx.z ? bias1 : bias0;
    float* C = blockIdx.z ? C1 : C0;
    gemm_body(A, B, bias, C, M, N, K, blockIdx.x * BN, blockIdx.y * BM, swh);
}

// ---------------- persistent encoder LSTM (fwd + bwd) ----------------
// 128 blocks: [0,64) fwd, [64,128) bwd; 768 threads = 12 waves.
// Wave w owns ALL 4 gates of dim jg = wb*12+w; lane = 64-way K-split
// (12 k-values: k = 4*lane+e+256*i, conflict-free float4 LDS reads).
// Full-wave butterfly -> all lanes hold 4 gate sums; lanes' q4=lane&3 pick
// their gate, parallel transcendentals, 3 shfls recombine; c carried uniformly
// by all lanes; lane 0 publishes {tag,h} pair. ONE barrier per step; h_s
// double-buffered by parity (WAR-safe, see r3 notes).
__global__ __launch_bounds__(768, 1) void lstm_enc_k(
    const float* __restrict__ Xf, const float* __restrict__ Xb,
    const float* __restrict__ Whf, const float* __restrict__ Whb,
    float* __restrict__ enc, unsigned long long* __restrict__ pairsE,
    unsigned long long* __restrict__ pairsD, float* __restrict__ c0) {
    const int dir = blockIdx.x >> 6;
    const int wb  = blockIdx.x & 63;
    const float* X  = dir ? Xb : Xf;
    const float* Wh = dir ? Whb : Whf;
    unsigned long long* pp = pairsE + (size_t)dir * 1536;  // [2par][768]
    const int tid = threadIdx.x;
    const int w = tid >> 6, lane = tid & 63, q4 = lane & 3;
    const int jg = wb * 12 + w;

    float wgt[3][4][4];  // [chunk][e][gate]
    #pragma unroll
    for (int i = 0; i < 3; ++i)
        #pragma unroll
        for (int e = 0; e < 4; ++e) {
            int k = 4 * lane + e + 256 * i;
            #pragma unroll
            for (int g = 0; g < 4; ++g)
                wgt[i][e][g] = Wh[(size_t)k * G4_ + g * H_ + jg];
        }

    __shared__ float h_s[2][768];
    float c = 0.f;

    for (int t = 0; t < SEQ_; ++t) {
        const int row = dir ? (SEQ_ - 1 - t) : t;
        float xq = X[(size_t)row * G4_ + wb * 48 + w * 4 + q4];  // prefetch

        const int par = t & 1;
        unsigned long long* p = pp + par * 768 + tid;
        unsigned long long v = __hip_atomic_load(p, __ATOMIC_RELAXED, __HIP_MEMORY_SCOPE_AGENT);
        while ((unsigned)(v >> 32) != (unsigned)t)
            v = __hip_atomic_load(p, __ATOMIC_RELAXED, __HIP_MEMORY_SCOPE_AGENT);
        h_s[par][tid] = __uint_as_float((unsigned)v);
        __syncthreads();

        float a0 = 0.f, a1 = 0.f, a2 = 0.f, a3 = 0.f;
        #pragma unroll
        for (int i = 0; i < 3; ++i) {
            const float4 hv = *(const float4*)&h_s[par][4 * lane + 256 * i];
            a0 += wgt[i][0][0] * hv.x + wgt[i][1][0] * hv.y + wgt[i][2][0] * hv.z + wgt[i][3][0] * hv.w;
            a1 += wgt[i][0][1] * hv.x + wgt[i][1][1] * hv.y + wgt[i][2][1] * hv.z + wgt[i][3][1] * hv.w;
            a2 += wgt[i][0][2] * hv.x + wgt[i][1][2] * hv.y + wgt[i][2][2] * hv.z + wgt[i][3][2] * hv.w;
            a3 += wgt[i][0][3] * hv.x + wgt[i][1][3] * hv.y + wgt[i][2][3] * hv.z + wgt[i][3][3] * hv.w;
        }
        #pragma unroll
        for (int m = 1; m < 64; m <<= 1) {
            a0 += __shfl_xor(a0, m); a1 += __shfl_xor(a1, m);
            a2 += __shfl_xor(a2, m); a3 += __shfl_xor(a3, m);
        }
        float sg = (q4 == 0) ? a0 : (q4 == 1) ? a1 : (q4 == 2) ? a2 : a3;
        sg += xq;
        float tr = (q4 == 2) ? tanhf(sg) : sigf(sg);
        float I  = __shfl(tr, 0), Fv = __shfl(tr, 1);
        float G  = __shfl(tr, 2), O  = __shfl(tr, 3);
        c = Fv * c + I * G;
        float h = O * tanhf(c);
        if (lane == 0) {
            enc[(size_t)row * H2_ + dir * H_ + jg] = h;
            unsigned long long pk =
                ((unsigned long long)(unsigned)(t + 1) << 32) | (unsigned long long)__float_as_uint(h);
            __hip_atomic_store(pp + ((t + 1) & 1) * 768 + jg, pk,
                               __ATOMIC_RELAXED, __HIP_MEMORY_SCOPE_AGENT);
            if (t == SEQ_ - 1) {
                __hip_atomic_store(pairsD + (size_t)(dir * H_ + jg),
                                   (unsigned long long)__float_as_uint(h),
                                   __ATOMIC_RELAXED, __HIP_MEMORY_SCOPE_AGENT);
                c0[dir * H_ + jg] = c;
            }
        }
    }
}

// ---------------- persistent decoder LSTM ----------------
// Same structure: 128 blocks x 12 waves; wave w owns dim jg = wb*12+w of 1536;
// lane k-chunk = 24 values (6 float4 chunks); thread polls 2 pairs.
__global__ __launch_bounds__(768, 1) void lstm_dec_k(
    const float* __restrict__ Xd, const float* __restrict__ Wh,
    float* __restrict__ Hn, unsigned long long* __restrict__ pairs,
    const float* __restrict__ c0) {
    const int wb = blockIdx.x;
    const int tid = threadIdx.x;
    const int w = tid >> 6, lane = tid & 63, q4 = lane & 3;
    const int jg = wb * 12 + w;

    float wgt[6][4][4];
    #pragma unroll
    for (int i = 0; i < 6; ++i)
        #pragma unroll
        for (int e = 0; e < 4; ++e) {
            int k = 4 * lane + e + 256 * i;
            #pragma unroll
            for (int g = 0; g < 4; ++g)
                wgt[i][e][g] = Wh[(size_t)k * G8_ + g * H2_ + jg];
        }

    __shared__ float h_s[2][1536];
    float c = c0[jg];

    for (int t = 0; t < T_; ++t) {
        float xq = Xd[(size_t)t * G8_ + wb * 48 + w * 4 + q4];

        const int par = t & 1;
        unsigned long long* p0 = pairs + par * 1536 + tid;
        unsigned long long* p1 = p0 + 768;
        unsigned long long v0 = __hip_atomic_load(p0, __ATOMIC_RELAXED, __HIP_MEMORY_SCOPE_AGENT);
        unsigned long long v1 = __hip_atomic_load(p1, __ATOMIC_RELAXED, __HIP_MEMORY_SCOPE_AGENT);
        while ((unsigned)(v0 >> 32) != (unsigned)t)
            v0 = __hip_atomic_load(p0, __ATOMIC_RELAXED, __HIP_MEMORY_SCOPE_AGENT);
        while ((unsigned)(v1 >> 32) != (unsigned)t)
            v1 = __hip_atomic_load(p1, __ATOMIC_RELAXED, __HIP_MEMORY_SCOPE_AGENT);
        h_s[par][tid]       = __uint_as_float((unsigned)v0);
        h_s[par][tid + 768] = __uint_as_float((unsigned)v1);
        __syncthreads();

        float a0 = 0.f, a1 = 0.f, a2 = 0.f, a3 = 0.f;
        #pragma unroll
        for (int i = 0; i < 6; ++i) {
            const float4 hv = *(const float4*)&h_s[par][4 * lane + 256 * i];
            a0 += wgt[i][0][0] * hv.x + wgt[i][1][0] * hv.y + wgt[i][2][0] * hv.z + wgt[i][3][0] * hv.w;
            a1 += wgt[i][0][1] * hv.x + wgt[i][1][1] * hv.y + wgt[i][2][1] * hv.z + wgt[i][3][1] * hv.w;
            a2 += wgt[i][0][2] * hv.x + wgt[i][1][2] * hv.y + wgt[i][2][2] * hv.z + wgt[i][3][2] * hv.w;
            a3 += wgt[i][0][3] * hv.x + wgt[i][1][3] * hv.y + wgt[i][2][3] * hv.z + wgt[i][3][3] * hv.w;
        }
        #pragma unroll
        for (int m = 1; m < 64; m <<= 1) {
            a0 += __shfl_xor(a0, m); a1 += __shfl_xor(a1, m);
            a2 += __shfl_xor(a2, m); a3 += __shfl_xor(a3, m);
        }
        float sg = (q4 == 0) ? a0 : (q4 == 1) ? a1 : (q4 == 2) ? a2 : a3;
        sg += xq;
        float tr = (q4 == 2) ? tanhf(sg) : sigf(sg);
        float I  = __shfl(tr, 0), Fv = __shfl(tr, 1);
        float G  = __shfl(tr, 2), O  = __shfl(tr, 3);
        c = Fv * c + I * G;
        float h = O * tanhf(c);
        if (lane == 0) {
            Hn[(size_t)t * H2_ + jg] = h;
            unsigned long long pk =
                ((unsigned long long)(unsigned)(t + 1) << 32) | (unsigned long long)__float_as_uint(h);
            __hip_atomic_store(pairs + ((t + 1) & 1) * 1536 + jg, pk,
                               __ATOMIC_RELAXED, __HIP_MEMORY_SCOPE_AGENT);
        }
    }
}

// ---------------- scores: out[t][a] = Amat[t] . enc[t*32+a] ----------------
__global__ void score_k(const float* __restrict__ Amat, const float* __restrict__ enc,
                        float* __restrict__ outp) {
    int t = blockIdx.x, tid = threadIdx.x;
    __shared__ float a_s[H2_];
    for (int i = tid; i < H2_; i += 256) a_s[i] = Amat[(size_t)t * H2_ + i];
    __syncthreads();
    int aa = tid >> 3, p = tid & 7;
    const float4* e = (const float4*)(enc + (size_t)(t * A_ + aa) * H2_ + p * 192);
    const float4* ap = (const float4*)(a_s + p * 192);
    float s = 0.f;
    #pragma unroll
    for (int i = 0; i < 48; ++i) {
        float4 av = ap[i], ev = e[i];
        s += av.x * ev.x + av.y * ev.y + av.z * ev.z + av.w * ev.w;
    }
    s += __shfl_xor(s, 1); s += __shfl_xor(s, 2); s += __shfl_xor(s, 4);
    if (p == 0) outp[t * A_ + aa] = s;
}

// ---------------- host launch ----------------
extern "C" void kernel_launch(void* const* d_in, const int* in_sizes, int n_in,
                              void* d_out, int out_size, void* d_ws, size_t ws_size,
                              hipStream_t stream) {
    const int*   lattice = (const int*)d_in[0];
    const int*   inputs  = (const int*)d_in[2];
    const int*   gold    = (const int*)d_in[4];
    const int*   sos     = (const int*)d_in[5];
    const float* emb     = (const float*)d_in[6];
    const float* tok     = (const float*)d_in[7];
    const float* Wxf = (const float*)d_in[8];
    const float* Whf = (const float*)d_in[9];
    const float* bf  = (const float*)d_in[10];
    const float* Wxb = (const float*)d_in[11];
    const float* Whb = (const float*)d_in[12];
    const float* bb  = (const float*)d_in[13];
    const float* dWx = (const float*)d_in[14];
    const float* dWh = (const float*)d_in[15];
    const float* db  = (const float*)d_in[16];
    const float* aW  = (const float*)d_in[17];
    float* ws  = (float*)d_ws;
    float* out = (float*)d_out;

    float* packed = ws + OFF_PACKED;
    float* Xf     = ws + OFF_XF;
    float* Xb     = ws + OFF_XB;
    float* Xd     = ws + OFF_XD;
    float* xdin   = ws + OFF_XDIN;
    float* enc    = ws + OFF_ENC;
    float* Hn     = ws + OFF_HN;
    float* Amat   = ws + OFF_AMAT;
    float* c0     = ws + OFF_C0;
    unsigned long long* pairsE = (unsigned long long*)(ws + OFF_PAIRS_E);
    unsigned long long* pairsD = (unsigned long long*)(ws + OFF_PAIRS_D);

    // reset pair tags (graph-replay safe; {tag=0,val=0} == initial h state)
    hipMemsetAsync((char*)d_ws + OFF_PAIRS_E * sizeof(float), 0, MEMSET_BYTES, stream);

    embed_k<<<SEQ_ + T_, 256, 0, stream>>>(lattice, inputs, gold, sos, emb, tok,
                                           packed, xdin);
    gemm_bias2_k<<<dim3(G4_ / BN, SEQ_ / BM, 2), 256, 0, stream>>>(
        packed, Wxf, bf, Xf, Wxb, bb, Xb, SEQ_, G4_, FE_, H_);
    gemm_bias_k<<<dim3(G8_ / BN, 1), 256, 0, stream>>>(xdin, dWx, db, Xd,
                                                       T_, G8_, DDEC_, H2_);
    lstm_enc_k<<<128, 768, 0, stream>>>(Xf, Xb, Whf, Whb, enc, pairsE, pairsD, c0);
    lstm_dec_k<<<128, 768, 0, stream>>>(Xd, dWh, Hn, pairsD, c0);
    gemm_bias_k<<<dim3(H2_ / BN, 1), 256, 0, stream>>>(Hn, aW, nullptr, Amat,
                                                       T_, H2_, H2_, 0);
    score_k<<<T_, 256, 0, stream>>>(Amat, enc, out);
}

// Round 4
// 3223.910 us; speedup vs baseline: 1.5682x; 1.5682x over previous
//
#include <hip/hip_runtime.h>
#include <cstddef>
#include <cstdint>

// ---------------- problem dims ----------------
#define T_ 32
#define A_ 32
#define F_ 4
#define E_ 256
#define FE_ 1024
#define H_ 768
#define H2_ 1536
#define G4_ 3072     // 4*H
#define G8_ 6144     // 4*H2
#define DTOK_ 256
#define DDEC_ 1280
#define SEQ_ 1024    // T*A

// ---------------- ws layout (float offsets) ----------------
constexpr size_t OFF_PACKED  = 0;                          // 1024*1024
constexpr size_t OFF_XF      = OFF_PACKED + 1024ull*1024;  // 1024*3072 (swizzled)
constexpr size_t OFF_XB      = OFF_XF + 1024ull*3072;
constexpr size_t OFF_XD      = OFF_XB + 1024ull*3072;      // 32*6144 (swizzled)
constexpr size_t OFF_XDIN    = OFF_XD + 32*6144;           // 32*1280
constexpr size_t OFF_ENC     = OFF_XDIN + 32*1280;         // 1024*1536
constexpr size_t OFF_HN      = OFF_ENC + 1024ull*1536;     // 32*1536
constexpr size_t OFF_AMAT    = OFF_HN + 32*1536;           // 32*1536
constexpr size_t OFF_C0      = OFF_AMAT + 32*1536;         // 1536
constexpr size_t OFF_PAIRS_E = OFF_C0 + 1536;              // 2dir x 2par x 768 u64 = 6144 floats
constexpr size_t OFF_PAIRS_D = OFF_PAIRS_E + 6144;         // 2par x 1536 u64 = 6144 floats
constexpr size_t MEMSET_BYTES = (6144 + 6144) * 4;         // 49152

__device__ __forceinline__ float sigf(float x) { return 1.f / (1.f + __expf(-x)); }

// ---------------- embed + decoder-input gather ----------------
__global__ void embed_k(const int* __restrict__ lattice, const int* __restrict__ inputs,
                        const int* __restrict__ gold, const int* __restrict__ sos,
                        const float* __restrict__ emb, const float* __restrict__ tok_emb,
                        float* __restrict__ packed, float* __restrict__ xdec_in) {
    int b = blockIdx.x, tid = threadIdx.x;
    if (b < SEQ_) {
        #pragma unroll
        for (int f = 0; f < F_; ++f) {
            int vid = lattice[b * F_ + f];
            packed[(size_t)b * FE_ + f * E_ + tid] = emb[(size_t)vid * E_ + tid];
        }
    } else {
        int t = b - SEQ_;  // 0..31
        for (int j = tid; j < DDEC_; j += 256) {
            float v;
            if (j < FE_) {
                int f = j >> 8, e2 = j & 255;
                int vid = (t == 0) ? sos[f]
                                   : lattice[(((t - 1) * A_) + gold[t - 1]) * F_ + f];
                v = emb[(size_t)vid * E_ + e2];
            } else {
                v = tok_emb[(size_t)inputs[t] * DTOK_ + (j - FE_)];
            }
            xdec_in[(size_t)t * DDEC_ + j] = v;
        }
    }
}

// ---------------- fp32 tiled GEMM: C[M,N] = A[M,K] @ B[K,N] + bias ----------------
// swh != 0: gate-interleaved output swizzle for the LSTM consumers:
//   n = q*swh + j  -> n' = (j/12)*48 + (j%12)*4 + q.   (q tile-uniform, swh%128==0)
#define BM 128
#define BN 128
#define BK 8
__device__ __forceinline__ void gemm_body(
    const float* __restrict__ A, const float* __restrict__ B,
    const float* __restrict__ bias, float* __restrict__ C,
    int M, int N, int K, int n0, int m0, int swh) {
    __shared__ float As[BK][BM + 4];
    __shared__ float Bs[BK][BN + 4];
    int tid = threadIdx.x;
    int tx = tid & 15, ty = tid >> 4;
    int lam = tid >> 1, lak = (tid & 1) * 4;
    int lbk = tid >> 5, lbn = (tid & 31) * 4;
    float acc[8][8] = {};
    for (int k0 = 0; k0 < K; k0 += BK) {
        float4 av = make_float4(0.f, 0.f, 0.f, 0.f);
        if (m0 + lam < M)
            av = *(const float4*)(A + (size_t)(m0 + lam) * K + k0 + lak);
        float4 bv = *(const float4*)(B + (size_t)(k0 + lbk) * N + n0 + lbn);
        __syncthreads();
        As[lak + 0][lam] = av.x; As[lak + 1][lam] = av.y;
        As[lak + 2][lam] = av.z; As[lak + 3][lam] = av.w;
        *(float4*)&Bs[lbk][lbn] = bv;
        __syncthreads();
        #pragma unroll
        for (int kk = 0; kk < BK; ++kk) {
            float a[8], b[8];
            *(float4*)&a[0] = *(const float4*)&As[kk][ty * 8];
            *(float4*)&a[4] = *(const float4*)&As[kk][ty * 8 + 4];
            *(float4*)&b[0] = *(const float4*)&Bs[kk][tx * 8];
            *(float4*)&b[4] = *(const float4*)&Bs[kk][tx * 8 + 4];
            #pragma unroll
            for (int i = 0; i < 8; ++i)
                #pragma unroll
                for (int j = 0; j < 8; ++j)
                    acc[i][j] += a[i] * b[j];
        }
    }
    int qg = 0, jb = 0;
    if (swh) { qg = n0 / swh; jb = n0 - qg * swh; }
    #pragma unroll
    for (int i = 0; i < 8; ++i) {
        int m = m0 + ty * 8 + i;
        if (m >= M) break;
        #pragma unroll
        for (int j = 0; j < 8; ++j) {
            int n = n0 + tx * 8 + j;
            float bb = bias ? bias[n] : 0.f;
            float v = acc[i][j] + bb;
            if (swh) {
                int jc = jb + tx * 8 + j;
                n = (jc / 12) * 48 + (jc % 12) * 4 + qg;
            }
            C[(size_t)m * N + n] = v;
        }
    }
}

__global__ __launch_bounds__(256) void gemm_bias_k(
    const float* __restrict__ A, const float* __restrict__ B,
    const float* __restrict__ bias, float* __restrict__ C,
    int M, int N, int K, int swh) {
    gemm_body(A, B, bias, C, M, N, K, blockIdx.x * BN, blockIdx.y * BM, swh);
}

__global__ __launch_bounds__(256) void gemm_bias2_k(
    const float* __restrict__ A,
    const float* __restrict__ B0, const float* __restrict__ bias0, float* __restrict__ C0,
    const float* __restrict__ B1, const float* __restrict__ bias1, float* __restrict__ C1,
    int M, int N, int K, int swh) {
    const float* B = blockIdx.z ? B1 : B0;
    const float* bias = blockIdx.z ? bias1 : bias0;
    float* C = blockIdx.z ? C1 : C0;
    gemm_body(A, B, bias, C, M, N, K, blockIdx.x * BN, blockIdx.y * BM, swh);
}

// ---------------- persistent encoder LSTM (fwd + bwd) ----------------
// 128 blocks: [0,64) fwd, [64,128) bwd; 768 threads = 12 waves.
// Wave w owns dim jg = wb*12+w (all 4 gates); lane = 64-way K-split (12 h/lane,
// register weights pinned via asm "+v"). Intra-16 DPP reduce -> part[4][64] LDS
// -> barrier -> wave 0 lanes 0-47 do gate combine + transcendentals in parallel
// (quad shfls recombine), lanes 0-11 publish enc + {tag,h} pairs as single
// coalesced bursts. 2 barriers/step; h_s double-buffered by parity.
__global__ __launch_bounds__(768, 1) void lstm_enc_k(
    const float* __restrict__ Xf, const float* __restrict__ Xb,
    const float* __restrict__ Whf, const float* __restrict__ Whb,
    float* __restrict__ enc, unsigned long long* __restrict__ pairsE,
    unsigned long long* __restrict__ pairsD, float* __restrict__ c0) {
    const int dir = blockIdx.x >> 6;
    const int wb  = blockIdx.x & 63;
    const float* X  = dir ? Xb : Xf;
    const float* Wh = dir ? Whb : Whf;
    unsigned long long* pp = pairsE + (size_t)dir * 1536;  // [2par][768]
    const int tid = threadIdx.x;
    const int w = tid >> 6, lane = tid & 63;
    const int g16 = lane >> 4;
    const int jg = wb * 12 + w;
    const int d = lane >> 2, q = lane & 3;   // tail mapping (wave 0)

    float wgt[3][4][4];  // [chunk][e][gate]
    #pragma unroll
    for (int i = 0; i < 3; ++i)
        #pragma unroll
        for (int e = 0; e < 4; ++e) {
            int k = 4 * lane + e + 256 * i;
            #pragma unroll
            for (int g = 0; g < 4; ++g)
                wgt[i][e][g] = Wh[(size_t)k * G4_ + g * H_ + jg];
        }
    // pin weights in VGPRs (defeat rematerialization/reload)
    #pragma unroll
    for (int i = 0; i < 3; ++i)
        #pragma unroll
        for (int e = 0; e < 4; ++e)
            #pragma unroll
            for (int g = 0; g < 4; ++g)
                asm volatile("" : "+v"(wgt[i][e][g]));

    __shared__ float h_s[2][768];
    __shared__ float part[4][64];
    float c = 0.f;

    for (int t = 0; t < SEQ_; ++t) {
        const int row = dir ? (SEQ_ - 1 - t) : t;
        float xq = 0.f;
        if (w == 0 && lane < 48) xq = X[(size_t)row * G4_ + wb * 48 + lane];  // prefetch

        const int par = t & 1;
        unsigned long long* p = pp + par * 768 + tid;
        unsigned long long v = __hip_atomic_load(p, __ATOMIC_RELAXED, __HIP_MEMORY_SCOPE_AGENT);
        while ((unsigned)(v >> 32) != (unsigned)t)
            v = __hip_atomic_load(p, __ATOMIC_RELAXED, __HIP_MEMORY_SCOPE_AGENT);
        h_s[par][tid] = __uint_as_float((unsigned)v);
        __syncthreads();                                   // A: h_s ready

        float a0 = 0.f, a1 = 0.f, a2 = 0.f, a3 = 0.f;
        #pragma unroll
        for (int i = 0; i < 3; ++i) {
            const float4 hv = *(const float4*)&h_s[par][4 * lane + 256 * i];
            a0 += wgt[i][0][0] * hv.x + wgt[i][1][0] * hv.y + wgt[i][2][0] * hv.z + wgt[i][3][0] * hv.w;
            a1 += wgt[i][0][1] * hv.x + wgt[i][1][1] * hv.y + wgt[i][2][1] * hv.z + wgt[i][3][1] * hv.w;
            a2 += wgt[i][0][2] * hv.x + wgt[i][1][2] * hv.y + wgt[i][2][2] * hv.z + wgt[i][3][2] * hv.w;
            a3 += wgt[i][0][3] * hv.x + wgt[i][1][3] * hv.y + wgt[i][2][3] * hv.z + wgt[i][3][3] * hv.w;
        }
        // intra-16 reduce (cheap DPP)
        #pragma unroll
        for (int m = 1; m < 16; m <<= 1) {
            a0 += __shfl_xor(a0, m); a1 += __shfl_xor(a1, m);
            a2 += __shfl_xor(a2, m); a3 += __shfl_xor(a3, m);
        }
        if ((lane & 15) == 0)
            *(float4*)&part[g16][w * 4] = make_float4(a0, a1, a2, a3);
        __syncthreads();                                   // B: partials ready

        if (w == 0) {
            // lanes 0-47: (dim d, gate q); lanes 48-63 compute garbage, unused
            float s = part[0][lane] + part[1][lane] + part[2][lane] + part[3][lane] + xq;
            float tr = (q == 2) ? tanhf(s) : sigf(s);
            float b1 = __shfl_xor(tr, 1), b2 = __shfl_xor(tr, 2), b3 = __shfl_xor(tr, 3);
            float I  = (q == 0) ? tr : (q == 1) ? b1 : (q == 2) ? b2 : b3;
            float Fv = (q == 0) ? b1 : (q == 1) ? tr : (q == 2) ? b3 : b2;
            float G  = (q == 0) ? b2 : (q == 1) ? b3 : (q == 2) ? tr : b1;
            float O  = (q == 0) ? b3 : (q == 1) ? b2 : (q == 2) ? b1 : tr;
            c = Fv * c + I * G;
            float h = O * tanhf(c);
            float hc = __shfl(h, lane * 4);                // compact dims -> lanes 0-11
            if (lane < 12) {
                enc[(size_t)row * H2_ + dir * H_ + wb * 12 + lane] = hc;
                unsigned long long pk = ((unsigned long long)(unsigned)(t + 1) << 32)
                                      | (unsigned long long)__float_as_uint(hc);
                __hip_atomic_store(pp + ((t + 1) & 1) * 768 + wb * 12 + lane, pk,
                                   __ATOMIC_RELAXED, __HIP_MEMORY_SCOPE_AGENT);
            }
            if (t == SEQ_ - 1) {
                float cc = __shfl(c, lane * 4);
                if (lane < 12) {
                    __hip_atomic_store(pairsD + (size_t)(dir * H_ + wb * 12 + lane),
                                       (unsigned long long)__float_as_uint(hc),
                                       __ATOMIC_RELAXED, __HIP_MEMORY_SCOPE_AGENT);
                    c0[dir * H_ + wb * 12 + lane] = cc;
                }
            }
        }
    }
}

// ---------------- persistent decoder LSTM ----------------
// 128 blocks x 12 waves; wave w owns dim jg = wb*12+w of 1536; K=1536 ->
// 96 pinned register weights/thread; thread polls pairs tid and tid+768.
__global__ __launch_bounds__(768, 1) void lstm_dec_k(
    const float* __restrict__ Xd, const float* __restrict__ Wh,
    float* __restrict__ Hn, unsigned long long* __restrict__ pairs,
    const float* __restrict__ c0) {
    const int wb = blockIdx.x;
    const int tid = threadIdx.x;
    const int w = tid >> 6, lane = tid & 63;
    const int g16 = lane >> 4;
    const int jg = wb * 12 + w;
    const int d = lane >> 2, q = lane & 3;

    float wgt[6][4][4];
    #pragma unroll
    for (int i = 0; i < 6; ++i)
        #pragma unroll
        for (int e = 0; e < 4; ++e) {
            int k = 4 * lane + e + 256 * i;
            #pragma unroll
            for (int g = 0; g < 4; ++g)
                wgt[i][e][g] = Wh[(size_t)k * G8_ + g * H2_ + jg];
        }
    #pragma unroll
    for (int i = 0; i < 6; ++i)
        #pragma unroll
        for (int e = 0; e < 4; ++e)
            #pragma unroll
            for (int g = 0; g < 4; ++g)
                asm volatile("" : "+v"(wgt[i][e][g]));

    __shared__ float h_s[2][1536];
    __shared__ float part[4][64];
    float c = (w == 0 && lane < 48) ? c0[wb * 12 + d] : 0.f;

    for (int t = 0; t < T_; ++t) {
        float xq = 0.f;
        if (w == 0 && lane < 48) xq = Xd[(size_t)t * G8_ + wb * 48 + lane];

        const int par = t & 1;
        unsigned long long* p0 = pairs + par * 1536 + tid;
        unsigned long long* p1 = p0 + 768;
        unsigned long long v0 = __hip_atomic_load(p0, __ATOMIC_RELAXED, __HIP_MEMORY_SCOPE_AGENT);
        unsigned long long v1 = __hip_atomic_load(p1, __ATOMIC_RELAXED, __HIP_MEMORY_SCOPE_AGENT);
        while ((unsigned)(v0 >> 32) != (unsigned)t)
            v0 = __hip_atomic_load(p0, __ATOMIC_RELAXED, __HIP_MEMORY_SCOPE_AGENT);
        while ((unsigned)(v1 >> 32) != (unsigned)t)
            v1 = __hip_atomic_load(p1, __ATOMIC_RELAXED, __HIP_MEMORY_SCOPE_AGENT);
        h_s[par][tid]       = __uint_as_float((unsigned)v0);
        h_s[par][tid + 768] = __uint_as_float((unsigned)v1);
        __syncthreads();                                   // A

        float a0 = 0.f, a1 = 0.f, a2 = 0.f, a3 = 0.f;
        #pragma unroll
        for (int i = 0; i < 6; ++i) {
            const float4 hv = *(const float4*)&h_s[par][4 * lane + 256 * i];
            a0 += wgt[i][0][0] * hv.x + wgt[i][1][0] * hv.y + wgt[i][2][0] * hv.z + wgt[i][3][0] * hv.w;
            a1 += wgt[i][0][1] * hv.x + wgt[i][1][1] * hv.y + wgt[i][2][1] * hv.z + wgt[i][3][1] * hv.w;
            a2 += wgt[i][0][2] * hv.x + wgt[i][1][2] * hv.y + wgt[i][2][2] * hv.z + wgt[i][3][2] * hv.w;
            a3 += wgt[i][0][3] * hv.x + wgt[i][1][3] * hv.y + wgt[i][2][3] * hv.z + wgt[i][3][3] * hv.w;
        }
        #pragma unroll
        for (int m = 1; m < 16; m <<= 1) {
            a0 += __shfl_xor(a0, m); a1 += __shfl_xor(a1, m);
            a2 += __shfl_xor(a2, m); a3 += __shfl_xor(a3, m);
        }
        if ((lane & 15) == 0)
            *(float4*)&part[g16][w * 4] = make_float4(a0, a1, a2, a3);
        __syncthreads();                                   // B

        if (w == 0) {
            float s = part[0][lane] + part[1][lane] + part[2][lane] + part[3][lane] + xq;
            float tr = (q == 2) ? tanhf(s) : sigf(s);
            float b1 = __shfl_xor(tr, 1), b2 = __shfl_xor(tr, 2), b3 = __shfl_xor(tr, 3);
            float I  = (q == 0) ? tr : (q == 1) ? b1 : (q == 2) ? b2 : b3;
            float Fv = (q == 0) ? b1 : (q == 1) ? tr : (q == 2) ? b3 : b2;
            float G  = (q == 0) ? b2 : (q == 1) ? b3 : (q == 2) ? tr : b1;
            float O  = (q == 0) ? b3 : (q == 1) ? b2 : (q == 2) ? b1 : tr;
            c = Fv * c + I * G;
            float h = O * tanhf(c);
            float hc = __shfl(h, lane * 4);
            if (lane < 12) {
                Hn[(size_t)t * H2_ + wb * 12 + lane] = hc;
                unsigned long long pk = ((unsigned long long)(unsigned)(t + 1) << 32)
                                      | (unsigned long long)__float_as_uint(hc);
                __hip_atomic_store(pairs + ((t + 1) & 1) * 1536 + wb * 12 + lane, pk,
                                   __ATOMIC_RELAXED, __HIP_MEMORY_SCOPE_AGENT);
            }
        }
    }
}

// ---------------- scores: out[t][a] = Amat[t] . enc[t*32+a] ----------------
__global__ void score_k(const float* __restrict__ Amat, const float* __restrict__ enc,
                        float* __restrict__ outp) {
    int t = blockIdx.x, tid = threadIdx.x;
    __shared__ float a_s[H2_];
    for (int i = tid; i < H2_; i += 256) a_s[i] = Amat[(size_t)t * H2_ + i];
    __syncthreads();
    int aa = tid >> 3, p = tid & 7;
    const float4* e = (const float4*)(enc + (size_t)(t * A_ + aa) * H2_ + p * 192);
    const float4* ap = (const float4*)(a_s + p * 192);
    float s = 0.f;
    #pragma unroll
    for (int i = 0; i < 48; ++i) {
        float4 av = ap[i], ev = e[i];
        s += av.x * ev.x + av.y * ev.y + av.z * ev.z + av.w * ev.w;
    }
    s += __shfl_xor(s, 1); s += __shfl_xor(s, 2); s += __shfl_xor(s, 4);
    if (p == 0) outp[t * A_ + aa] = s;
}

// ---------------- host launch ----------------
extern "C" void kernel_launch(void* const* d_in, const int* in_sizes, int n_in,
                              void* d_out, int out_size, void* d_ws, size_t ws_size,
                              hipStream_t stream) {
    const int*   lattice = (const int*)d_in[0];
    const int*   inputs  = (const int*)d_in[2];
    const int*   gold    = (const int*)d_in[4];
    const int*   sos     = (const int*)d_in[5];
    const float* emb     = (const float*)d_in[6];
    const float* tok     = (const float*)d_in[7];
    const float* Wxf = (const float*)d_in[8];
    const float* Whf = (const float*)d_in[9];
    const float* bf  = (const float*)d_in[10];
    const float* Wxb = (const float*)d_in[11];
    const float* Whb = (const float*)d_in[12];
    const float* bb  = (const float*)d_in[13];
    const float* dWx = (const float*)d_in[14];
    const float* dWh = (const float*)d_in[15];
    const float* db  = (const float*)d_in[16];
    const float* aW  = (const float*)d_in[17];
    float* ws  = (float*)d_ws;
    float* out = (float*)d_out;

    float* packed = ws + OFF_PACKED;
    float* Xf     = ws + OFF_XF;
    float* Xb     = ws + OFF_XB;
    float* Xd     = ws + OFF_XD;
    float* xdin   = ws + OFF_XDIN;
    float* enc    = ws + OFF_ENC;
    float* Hn     = ws + OFF_HN;
    float* Amat   = ws + OFF_AMAT;
    float* c0     = ws + OFF_C0;
    unsigned long long* pairsE = (unsigned long long*)(ws + OFF_PAIRS_E);
    unsigned long long* pairsD = (unsigned long long*)(ws + OFF_PAIRS_D);

    // reset pair tags (graph-replay safe; {tag=0,val=0} == initial h state)
    hipMemsetAsync((char*)d_ws + OFF_PAIRS_E * sizeof(float), 0, MEMSET_BYTES, stream);

    embed_k<<<SEQ_ + T_, 256, 0, stream>>>(lattice, inputs, gold, sos, emb, tok,
                                           packed, xdin);
    gemm_bias2_k<<<dim3(G4_ / BN, SEQ_ / BM, 2), 256, 0, stream>>>(
        packed, Wxf, bf, Xf, Wxb, bb, Xb, SEQ_, G4_, FE_, H_);
    gemm_bias_k<<<dim3(G8_ / BN, 1), 256, 0, stream>>>(xdin, dWx, db, Xd,
                                                       T_, G8_, DDEC_, H2_);
    lstm_enc_k<<<128, 768, 0, stream>>>(Xf, Xb, Whf, Whb, enc, pairsE, pairsD, c0);
    lstm_dec_k<<<128, 768, 0, stream>>>(Xd, dWh, Hn, pairsD, c0);
    gemm_bias_k<<<dim3(H2_ / BN, 1), 256, 0, stream>>>(Hn, aW, nullptr, Amat,
                                                       T_, H2_, H2_, 0);
    score_k<<<T_, 256, 0, stream>>>(Amat, enc, out);
}